// Round 5
// baseline (440.716 us; speedup 1.0000x reference)
//
#include <hip/hip_runtime.h>
#include <hip/hip_bf16.h>

// Downsample: ternary-quantized conv3x3 stride2 pad1, NCHW.
// x:(32,384,64,64) f32, w:(384,384,3,3) f32, bias:(384,) f32 -> out:(32,384,32,32) f32
// Implicit GEMM: M=32768 (n,oh,ow), N=384 (o), K=3456 ((kh,kw,c)), bf16 MFMA.
// Round 5: round-4 with the nhwc coverage bug fixed — the LDS-free transpose
// dropped blockIdx.y and only wrote c in [0,64); grid is (2048, 6) again so all
// 384 channels are covered. conv_gemm keeps the flattened grid (o fastest) for
// L2/L3 x-reuse. No atomics anywhere (determinism).

#define CIN   384
#define HIN   64
#define WIN   64
#define OHW   32
#define KDIM  3456          // 9*384
#define NWELT 1327104       // 384*384*9
#define MDIM  32768         // 32*32*32

using bf16 = __hip_bfloat16;
typedef __attribute__((ext_vector_type(8))) short short8;   // MFMA A/B frag (8 bf16)
typedef __attribute__((ext_vector_type(4))) float floatx4;  // MFMA C/D frag

#define AS1 __attribute__((address_space(1)))
#define AS3 __attribute__((address_space(3)))
#define DMA16(g, l) __builtin_amdgcn_global_load_lds((const AS1 void*)(g), (AS3 void*)(l), 16, 0, 0)

// ws layout (floats): [0]=alpha, [1]=thr, [2..64)=62 partials; f[16..20) is
// REUSED as a 16B zero region (written by absum_final AFTER consuming partials).
// bytes [256, 256+100663296): x_nhwc bf16 [32][64][64][384]
// bytes [256+100663296, +2654208): Wq bf16 [384][3456] (k=(kh*3+kw)*384+c)
#define NPART  62
#define ZG_F   16
#define XN_OFF 256
#define WQ_OFF (256 + 100663296)

// ---- Stage 1: fixed-slot partial sums of |w| (no atomics -> deterministic) ----
__global__ void absum_part(const float* __restrict__ w, float* __restrict__ ws) {
    const float4* w4 = (const float4*)w;
    float s = 0.f;
    for (int i = blockIdx.x * 256 + threadIdx.x; i < NWELT / 4; i += NPART * 256) {
        float4 v = w4[i];
        s += fabsf(v.x) + fabsf(v.y) + fabsf(v.z) + fabsf(v.w);
    }
    for (int off = 32; off; off >>= 1) s += __shfl_down(s, off, 64);
    __shared__ float red[4];
    if ((threadIdx.x & 63) == 0) red[threadIdx.x >> 6] = s;
    __syncthreads();
    if (threadIdx.x == 0) ws[2 + blockIdx.x] = red[0] + red[1] + red[2] + red[3];
}

// ---- Stage 2: fixed-order final reduction; also zero the DMA guard region ----
__global__ void absum_final(float* __restrict__ ws) {
    if (threadIdx.x == 0) {
        float s = 0.f;
        for (int i = 0; i < NPART; ++i) s += ws[2 + i];
        float alpha = s * (1.0f / NWELT);
        ws[0] = alpha;
        ws[1] = 1e-3f * alpha;
        ws[ZG_F + 0] = 0.f; ws[ZG_F + 1] = 0.f;   // 16B zero guard (partials dead now)
        ws[ZG_F + 2] = 0.f; ws[ZG_F + 3] = 0.f;
    }
}

// ---- Ternary quantize, output-indexed (coalesced 2B writes; reads are L2/L3-hot) ----
__global__ void quant_kernel(const float* __restrict__ w, const float* __restrict__ ws,
                             bf16* __restrict__ wq) {
    int j = blockIdx.x * 256 + threadIdx.x;   // j = o*3456 + (kh*3+kw)*384 + c
    if (j >= NWELT) return;
    float thr = ws[1];
    int o = j / KDIM;
    int rmd = j - o * KDIM;
    int khkw = rmd / 384;
    int c = rmd - khkw * 384;
    float v = w[((o * 384 + c) * 9) + khkw];
    float q = (v > thr) ? 1.f : ((v < -thr) ? -1.f : 0.f);
    wq[j] = __float2bfloat16(q);
}

// ---- NCHW f32 -> NHWC bf16, direct (no LDS). grid=(2048, 6), block=256. ----
// Block covers (n,h) x 64 channels (c0 base = blockIdx.y*64). Thread t in [0,512):
// c-octet = t&7, w = t>>3. Reads: 8 scalar f32; per wave+j that is 8 runs of 32B
// (sibling wave reads the other half of each 64B line concurrently -> L1 hit).
// Writes: lanes 0..7 cover 128 contiguous bytes -> coalesced short8 stores.
__global__ void nhwc_kernel(const float* __restrict__ x, bf16* __restrict__ xn) {
    int n = blockIdx.x >> 6, h = blockIdx.x & 63;
    int cb = blockIdx.y * 64;
    const float* src = x + ((size_t)(n * CIN + cb) * HIN + h) * WIN;  // + c*4096 + w
    bf16* dst = xn + ((size_t)(n * HIN + h) * WIN) * CIN + cb;        // + w*384 + c
    #pragma unroll
    for (int i = 0; i < 2; ++i) {
        int t = threadIdx.x + i * 256;
        int c0 = (t & 7) * 8;
        int w = t >> 3;
        bf16 tmp[8];
        #pragma unroll
        for (int j = 0; j < 8; ++j)
            tmp[j] = __float2bfloat16(src[(size_t)(c0 + j) * 4096 + w]);
        *(short8*)(dst + (size_t)w * CIN + c0) = *(short8*)tmp;
    }
}

// ---- GEMM: D[o][m] = sum_k Wq[o][k] * X[m][k]. A=Wq, B=X. ----
// BM=128 (m), BNO=128 (o), BK=64. 4 waves, each 64x64 (4x4 frags of 16x16x32).
// LDS layout (per buffer, 128 rows x 64 k-elements, unpadded 128B rows):
//   slot(r, oct) at bytes r*128 + oct*16 holds global octet (oct ^ (r&7)) of row r.
// DMA coverage: call (wv,i) covers slots (wv*4+i)*64 + lane; lane's global octet
//   g = (lane&7) ^ (lane>>3), row r = (wv*4+i)*8 + (lane>>3).
// ds_read side: oct = (ks*4 + quad) ^ (lane&7)  -> <=2-way bank alias (free).
// Grid: flat 768; o = bid%3 fastest so the 3 o-tiles of one m-tile co-run (x reuse).
#define BM  128
#define BNO 128

__global__ __launch_bounds__(256) void conv_gemm(const bf16* __restrict__ xn,
                                                 const bf16* __restrict__ wq,
                                                 const float* __restrict__ ws,
                                                 const float* __restrict__ bias,
                                                 float* __restrict__ out,
                                                 const bf16* __restrict__ zg) {
    int bid = blockIdx.x;
    int o_base = (bid % 3) * BNO;
    int m_base = (bid / 3) * BM;
    __shared__ __align__(16) bf16 lW[BNO * 64];
    __shared__ __align__(16) bf16 lX[BM * 64];
    int tid = threadIdx.x;
    int lane = tid & 63;
    int wv = tid >> 6;
    int wo = (wv & 1) * 64;
    int wm = (wv >> 1) * 64;

    // per-thread fixed staging descriptors
    int g = (lane & 7) ^ (lane >> 3);          // global octet this lane DMAs
    const bf16* pw[4];
    const bf16* pxn[4];
    int oh2[4], ow2[4];
    bf16* ldsWb[4]; bf16* ldsXb[4];
    #pragma unroll
    for (int i = 0; i < 4; ++i) {
        int r = (wv * 4 + i) * 8 + (lane >> 3);          // row in tile [0,128)
        ldsWb[i] = &lW[(wv * 4 + i) * 512];              // wave-uniform 16B-slot base
        ldsXb[i] = &lX[(wv * 4 + i) * 512];
        pw[i] = wq + (size_t)(o_base + r) * KDIM + g * 8;
        int m = m_base + r;
        int n = m >> 10, oh = (m >> 5) & 31, ow = m & 31;
        pxn[i] = xn + (size_t)n * (HIN * WIN * CIN) + g * 8;
        oh2[i] = 2 * oh - 1;
        ow2[i] = 2 * ow - 1;
    }

    floatx4 acc[4][4];
    for (int i = 0; i < 4; ++i)
        for (int j = 0; j < 4; ++j)
            acc[i][j] = (floatx4){0.f, 0.f, 0.f, 0.f};

    for (int khkw = 0; khkw < 9; ++khkw) {
        int kh = khkw / 3, kw = khkw % 3;
        const bf16* pwk[4];
        const bf16* pxk[4];
        #pragma unroll
        for (int i = 0; i < 4; ++i) {
            pwk[i] = pw[i] + khkw * 384;
            int ih = oh2[i] + kh, iw = ow2[i] + kw;      // upper bound fine (<=63)
            bool valid = (ih >= 0) & (iw >= 0);
            pxk[i] = valid ? pxn[i] + (ih * WIN + iw) * CIN : (const bf16*)0;
        }
        for (int cc = 0; cc < 6; ++cc) {
            int coff = cc * 64;
            #pragma unroll
            for (int i = 0; i < 4; ++i)
                DMA16(pwk[i] + coff, ldsWb[i]);
            #pragma unroll
            for (int i = 0; i < 4; ++i) {
                const bf16* p = pxk[i] ? pxk[i] + coff : zg;
                DMA16(p, ldsXb[i]);
            }
            __syncthreads();
            #pragma unroll
            for (int ks = 0; ks < 2; ++ks) {
                int oct = ((ks * 4 + (lane >> 4)) ^ (lane & 7)) * 8;
                short8 af[4], bfr[4];
                #pragma unroll
                for (int i = 0; i < 4; ++i)
                    af[i] = *(const short8*)(&lW[(wo + i * 16 + (lane & 15)) * 64 + oct]);
                #pragma unroll
                for (int j = 0; j < 4; ++j)
                    bfr[j] = *(const short8*)(&lX[(wm + j * 16 + (lane & 15)) * 64 + oct]);
                #pragma unroll
                for (int i = 0; i < 4; ++i)
                    #pragma unroll
                    for (int j = 0; j < 4; ++j)
                        acc[i][j] = __builtin_amdgcn_mfma_f32_16x16x32_bf16(af[i], bfr[j], acc[i][j], 0, 0, 0);
            }
            __syncthreads();
        }
    }

    // epilogue: D row=(lane>>4)*4+reg = o, col=lane&15 = m -> coalesced along ow
    float alpha = ws[0];
    int quad = lane >> 4, colm = lane & 15;
    for (int i = 0; i < 4; ++i) {
        for (int j = 0; j < 4; ++j) {
            int mm = m_base + wm + j * 16 + colm;
            int n = mm >> 10, oh = (mm >> 5) & 31, ow = mm & 31;
            for (int r = 0; r < 4; ++r) {
                int o = o_base + wo + i * 16 + quad * 4 + r;
                out[((n * 384 + o) * OHW + oh) * OHW + ow] = alpha * acc[i][j][r] + bias[o];
            }
        }
    }
}

extern "C" void kernel_launch(void* const* d_in, const int* in_sizes, int n_in,
                              void* d_out, int out_size, void* d_ws, size_t ws_size,
                              hipStream_t stream) {
    (void)in_sizes; (void)n_in; (void)out_size; (void)ws_size;
    const float* x    = (const float*)d_in[0];
    const float* w    = (const float*)d_in[1];
    const float* bias = (const float*)d_in[2];
    float* out = (float*)d_out;
    float* wsf = (float*)d_ws;
    bf16* xn = (bf16*)((char*)d_ws + XN_OFF);
    bf16* wq = (bf16*)((char*)d_ws + WQ_OFF);
    const bf16* zg = (const bf16*)(wsf + ZG_F);

    absum_part<<<NPART, 256, 0, stream>>>(w, wsf);
    absum_final<<<1, 64, 0, stream>>>(wsf);
    quant_kernel<<<(NWELT + 255) / 256, 256, 0, stream>>>(w, wsf, wq);
    nhwc_kernel<<<dim3(2048, 6), 256, 0, stream>>>(x, xn);
    conv_gemm<<<(MDIM / BM) * 3, 256, 0, stream>>>(xn, wq, wsf, bias, out, zg);
}